// Round 15
// baseline (389.956 us; speedup 1.0000x reference)
//
#include <hip/hip_runtime.h>
#include <math.h>

// Problem constants (SwinBlock: B=4, H=W=224, C=96, WS=8, shift=4, NH=3, hd=32)
static constexpr int Hn   = 224;
static constexpr int Wn   = 224;
static constexpr int Cn   = 96;
static constexpr int Sft  = 4;     // WS/2
static constexpr int NWH  = 28;    // 224/8
static constexpr int NWPB = 784;   // 28*28
static constexpr int NW   = 3136;  // 4*784
static constexpr int GRID = 768;   // persistent: 3 blocks/CU x 256 CUs

typedef __attribute__((ext_vector_type(8))) short bf16x8;  // 8 bf16 in 4 VGPRs
typedef __attribute__((ext_vector_type(4))) float f32x4;
typedef __attribute__((ext_vector_type(4))) short s16x4;

// Native RNE float->bf16 (R11 win; 1 VALU op, rounding identical to manual RNE).
__device__ inline short f2bf(float f) {
    __bf16 h = (__bf16)f;
    return __builtin_bit_cast(short, h);
}

// Fast erf-based GELU (A&S 7.1.26, |eps_erf| <= 1.5e-7 -> invisible under the
// bf16 rounding that immediately follows).
__device__ inline float gelu_f(float a) {
    float u  = a * 0.70710678118654752f;
    float au = fabsf(u);
    float t  = __builtin_amdgcn_rcpf(fmaf(0.3275911f, au, 1.f));
    float e  = __expf(-u * u);
    float p  = t * fmaf(t, fmaf(t, fmaf(t, fmaf(t, 1.061405429f,
                        -1.453152027f), 1.421413741f), -0.284496736f),
                        0.254829592f);
    float er = fmaf(-p, e, 1.f);          // erf(|u|)
    er = (u < 0.f) ? -er : er;
    return 0.5f * a * (1.f + er);
}

// ---------------------------------------------------------------------------
// K0: convert ALL weights to bf16 into ws.
// layout (shorts): wqb[27648] | wob[9216] | w1b[36864] | w2b[36864]  (221184 B)
// ---------------------------------------------------------------------------
__global__ void prep_bf16(const float* __restrict__ wqkv, const float* __restrict__ wo,
                          const float* __restrict__ w1,   const float* __restrict__ w2,
                          short* __restrict__ ws) {
    int idx = blockIdx.x * 256 + threadIdx.x;
    if (idx < 27648)        ws[idx] = f2bf(wqkv[idx]);
    else if (idx < 36864)   ws[idx] = f2bf(wo[idx - 27648]);
    else if (idx < 73728)   ws[idx] = f2bf(w1[idx - 36864]);
    else if (idx < 110592)  ws[idx] = f2bf(w2[idx - 73728]);
}

// ---------------------------------------------------------------------------
// K1 (R15 = R14 + persistent grid + cross-window x prefetch): 3 blocks/CU.
// R14 confirmed: latency-bound (both pipes ~56% idle), barriers ~1%. The one
// untouched exposed-latency structure: each block's cold start (x-load ->
// barrier -> LN1, nothing to overlap in-block). Persistent 768-block grid,
// window-stride loop; thread prefetches its NEXT window's row-quarter
// (6 float4 = 24 VGPR) right after LN1 consumes xf -> ~whole-iteration
// latency hiding. P1/P7 switched to (row=tid>>2, quarter=tid&3) map (pure
// data movement, same values) so the prefetch is per-thread addressable;
// tbase LDS deleted (per-thread ALU decode). +1 barrier at loop end
// (P7-reads -> next xf-stores WAR).
// Arithmetic UNCHANGED from R14 -> absmax sentinel == 9.766e-4 exactly.
// Spill sentinel: FETCH ~39MB (24 extra live VGPRs; budget 168 @ 3 w/SIMD).
// LDS unions:
//  U[25600]   : xf f32 -> Q|K bf16 -> P bf16 -> st f32
//  h2b[13312] : LN1-out -> O -> LN2-out -> actQ1 (ping-pong)
//  vtact[13824]: vt (V^T) -> actQ0
// Fragment layouts (mfma_f32_16x16x32_bf16, m89-verified):
//  A: row=lane&15, k=(lane>>4)*8+j ; B: col=lane&15, same k ;
//  D: col=lane&15, row=(lane>>4)*4+r   (swapped: transpose of this)
// ---------------------------------------------------------------------------
static constexpr int LDH  = 104;  // h2b stride (shorts)
static constexpr int LDQK = 200;  // U as Q|K: stride (shorts): Q[0..95] K[96..191] pad8
static constexpr int LDVT = 72;   // vt stride (shorts): [ch 96][tok 64 pad8]
static constexpr int LDP  = 200;  // U as P: [tok][h*64+kv] pad8 (shorts)
static constexpr int LDXF = 100;  // U as xf: stride (floats)
static constexpr int LDST = 100;  // U as st: stride (floats)
static constexpr int LDAQ = 104;  // actQ stride (shorts), one 96-col quarter (==LDH)

__global__ __launch_bounds__(256, 3) void attn_mlp(
    const float* __restrict__ x,
    const float* __restrict__ ln1w, const float* __restrict__ ln1b,
    const short* __restrict__ wqb,  const float* __restrict__ bqkv,
    const short* __restrict__ wob,  const float* __restrict__ bo,
    const float* __restrict__ ln2w, const float* __restrict__ ln2b,
    const short* __restrict__ w1b,  const float* __restrict__ b1,
    const short* __restrict__ w2b,  const float* __restrict__ b2,
    float* __restrict__ out)
{
    __shared__ __align__(16) char  U[64 * 400];        // xf -> Q|K -> P -> st
    __shared__ __align__(16) short h2b[64 * LDH];      // LN1 -> O -> LN2 -> actQ1
    __shared__ __align__(16) short vtact[96 * LDVT];   // vt -> actQ0

    const int tid  = threadIdx.x;
    const int lane = tid & 63;
    const int wv   = __builtin_amdgcn_readfirstlane(tid >> 6);
    const int lr   = lane & 15;
    const int lk   = lane >> 4;
    const int wr   = wv >> 1;   // 2x2 wave split: row group (32 rows)
    const int wc   = wv & 1;    //                 col group
    const int lt   = tid >> 2;  // token row this thread owns (P1/LN/P7)
    const int lp   = tid & 3;   // quarter (24 cols)
    const int ti   = lt >> 3, tj = lt & 7;   // (i,j) within window for row lt

    // ---- prologue: decode + load first window's x quarter into registers ----
    int w = blockIdx.x;
    int tb;
    float4 vpre[6];
    {
        int b = w / NWPB, rem = w - b * NWPB;
        int wh = rem / NWH, ww = rem - wh * NWH;
        int hs  = wh * 8 + ti + Sft; if (hs  >= Hn) hs  -= Hn;
        int ws2 = ww * 8 + tj + Sft; if (ws2 >= Wn) ws2 -= Wn;
        tb = ((b * Hn + hs) * Wn + ws2) * Cn;
        const float4* xp = (const float4*)(x + tb + lp * 24);
        #pragma unroll
        for (int jj = 0; jj < 6; ++jj) vpre[jj] = xp[jj];
    }

    for (; w < NW; w += GRID) {
        // ---- P1: store prefetched x quarter -> xf ((lt,lp) map) ----
        float* xf = (float*)U;
        #pragma unroll
        for (int jj = 0; jj < 6; ++jj)
            *(float4*)&xf[lt * LDXF + lp * 24 + jj * 4] = vpre[jj];
        __syncthreads();                                   // xf ready

        // ---- P2: LN1 (4 lanes/token) — identical arithmetic to R14 ----
        {
            const int l = lt, p = lp;
            float s0 = 0.f, s1 = 0.f;
            #pragma unroll
            for (int c0 = 0; c0 < 24; ++c0) {
                float v = xf[l * LDXF + p * 24 + c0];
                s0 += v; s1 += v * v;
            }
            s0 += __shfl_xor(s0, 1); s1 += __shfl_xor(s1, 1);
            s0 += __shfl_xor(s0, 2); s1 += __shfl_xor(s1, 2);
            float mean = s0 * (1.f / 96.f);
            float var  = fmaxf(s1 * (1.f / 96.f) - mean * mean, 0.f);
            float rstd = rsqrtf(var + 1e-5f);
            #pragma unroll
            for (int c0 = 0; c0 < 24; ++c0) {
                int c = p * 24 + c0;
                float v = xf[l * LDXF + c];
                h2b[l * LDH + c] = f2bf((v - mean) * rstd * ln1w[c] + ln1b[c]);
            }
        }

        // ---- prefetch NEXT window's x quarter (global->regs; no LDS hazard) --
        int tbn = 0;
        {
            const int wn = w + GRID;
            if (wn < NW) {
                int b = wn / NWPB, rem = wn - b * NWPB;
                int wh = rem / NWH, ww = rem - wh * NWH;
                int hs  = wh * 8 + ti + Sft; if (hs  >= Hn) hs  -= Hn;
                int ws2 = ww * 8 + tj + Sft; if (ws2 >= Wn) ws2 -= Wn;
                tbn = ((b * Hn + hs) * Wn + ws2) * Cn;
                const float4* xp = (const float4*)(x + tbn + lp * 24);
                #pragma unroll
                for (int jj = 0; jj < 6; ++jj) vpre[jj] = xp[jj];
            }
        }
        __syncthreads();   // h2b ready; xf dead (fences Q/K overwrite)

        // ---- P3: QKV GEMM, 2x2 split. Q/K swapped -> packed s16x4; V -> vt --
        short* qk = (short*)U;
        short* vt = vtact;
        {
            bf16x8 aq[2][3];
            #pragma unroll
            for (int rt = 0; rt < 2; ++rt)
                #pragma unroll
                for (int ks = 0; ks < 3; ++ks)
                    aq[rt][ks] = *(const bf16x8*)&h2b[(wr * 32 + rt * 16 + lr) * LDH + ks * 32 + lk * 8];

            #pragma unroll 3
            for (int ct9 = 0; ct9 < 9; ++ct9) {
                const int ct = wc * 9 + ct9;
                const short* bp = wqb + (ct * 16 + lr) * 96 + lk * 8;
                bf16x8 b0 = *(const bf16x8*)(bp);
                bf16x8 b1 = *(const bf16x8*)(bp + 32);
                bf16x8 b2v = *(const bf16x8*)(bp + 64);
                if (ct < 12) {               // Q,K: swapped -> D^T, packed store
                    const float4 b4 = *(const float4*)&bqkv[ct * 16 + lk * 4];
                    #pragma unroll
                    for (int rt = 0; rt < 2; ++rt) {
                        f32x4 acc = (f32x4){0.f, 0.f, 0.f, 0.f};
                        acc = __builtin_amdgcn_mfma_f32_16x16x32_bf16(b0, aq[rt][0], acc, 0, 0, 0);
                        acc = __builtin_amdgcn_mfma_f32_16x16x32_bf16(b1, aq[rt][1], acc, 0, 0, 0);
                        acc = __builtin_amdgcn_mfma_f32_16x16x32_bf16(b2v, aq[rt][2], acc, 0, 0, 0);
                        const int tok = wr * 32 + rt * 16 + lr;
                        s16x4 pk;
                        pk[0] = f2bf(acc[0] + b4.x); pk[1] = f2bf(acc[1] + b4.y);
                        pk[2] = f2bf(acc[2] + b4.z); pk[3] = f2bf(acc[3] + b4.w);
                        *(s16x4*)&qk[tok * LDQK + ct * 16 + lk * 4] = pk;
                    }
                } else {                     // V: unswapped -> transposed vt store
                    const float bs = bqkv[ct * 16 + lr];
                    #pragma unroll
                    for (int rt = 0; rt < 2; ++rt) {
                        f32x4 acc = (f32x4){0.f, 0.f, 0.f, 0.f};
                        acc = __builtin_amdgcn_mfma_f32_16x16x32_bf16(aq[rt][0], b0, acc, 0, 0, 0);
                        acc = __builtin_amdgcn_mfma_f32_16x16x32_bf16(aq[rt][1], b1, acc, 0, 0, 0);
                        acc = __builtin_amdgcn_mfma_f32_16x16x32_bf16(aq[rt][2], b2v, acc, 0, 0, 0);
                        const int rb = wr * 32 + rt * 16;
                        s16x4 pk;
                        #pragma unroll
                        for (int r = 0; r < 4; ++r) pk[r] = f2bf(acc[r] + bs);
                        *(s16x4*)&vt[(ct * 16 + lr - 192) * LDVT + rb + lk * 4] = pk;
                    }
                }
            }
        }
        __syncthreads();   // Q,K,V visible to all waves

        // ---- P4: S = QK^T per head (wave -> query row-tile wv), softmax ----
        short* pb = (short*)U;   // P overwrites Q|K after the barrier below
        {
            f32x4 accs[3][4];
            #pragma unroll
            for (int h = 0; h < 3; ++h) {
                bf16x8 aqf = *(const bf16x8*)&qk[(wv * 16 + lr) * LDQK + h * 32 + lk * 8];
                #pragma unroll
                for (int ct = 0; ct < 4; ++ct) {
                    bf16x8 bk = *(const bf16x8*)&qk[(ct * 16 + lr) * LDQK + 96 + h * 32 + lk * 8];
                    f32x4 z = (f32x4){0.f, 0.f, 0.f, 0.f};
                    accs[h][ct] = __builtin_amdgcn_mfma_f32_16x16x32_bf16(aqf, bk, z, 0, 0, 0);
                }
            }
            __syncthreads();   // every wave done reading K -> P may overwrite U

            const float scale = 0.17677669529663687f;  // 1/sqrt(32)
            float inv[3][4];
            #pragma unroll
            for (int h = 0; h < 3; ++h) {
                #pragma unroll
                for (int r = 0; r < 4; ++r) {
                    float m = fmaxf(fmaxf(accs[h][0][r], accs[h][1][r]),
                                    fmaxf(accs[h][2][r], accs[h][3][r]));
                    m = fmaxf(m, __shfl_xor(m, 1));
                    m = fmaxf(m, __shfl_xor(m, 2));
                    m = fmaxf(m, __shfl_xor(m, 4));
                    m = fmaxf(m, __shfl_xor(m, 8));
                    float s = 0.f;
                    #pragma unroll
                    for (int ct = 0; ct < 4; ++ct) {
                        float p = __expf((accs[h][ct][r] - m) * scale);
                        accs[h][ct][r] = p; s += p;
                    }
                    s += __shfl_xor(s, 1); s += __shfl_xor(s, 2);
                    s += __shfl_xor(s, 4); s += __shfl_xor(s, 8);
                    inv[h][r] = 1.f / s;
                }
            }
            // P -> bf16 LDS (rows of own wave only; no barrier needed)
            #pragma unroll
            for (int h = 0; h < 3; ++h)
                #pragma unroll
                for (int ct = 0; ct < 4; ++ct)
                    #pragma unroll
                    for (int r = 0; r < 4; ++r)
                        pb[(wv * 16 + lk * 4 + r) * LDP + h * 64 + ct * 16 + lr] =
                            f2bf(accs[h][ct][r]);

            // ---- P5: O = P V (deferred 1/sum), write O bf16 into h2b ----
            f32x4 acco[3][2];
            #pragma unroll
            for (int h = 0; h < 3; ++h)
                #pragma unroll
                for (int ct = 0; ct < 2; ++ct) acco[h][ct] = (f32x4){0.f, 0.f, 0.f, 0.f};
            #pragma unroll
            for (int h = 0; h < 3; ++h) {
                #pragma unroll
                for (int ks = 0; ks < 2; ++ks) {
                    bf16x8 ap = *(const bf16x8*)&pb[(wv * 16 + lr) * LDP + h * 64 + ks * 32 + lk * 8];
                    #pragma unroll
                    for (int ct = 0; ct < 2; ++ct) {
                        bf16x8 bv = *(const bf16x8*)&vt[(h * 32 + ct * 16 + lr) * LDVT + ks * 32 + lk * 8];
                        acco[h][ct] = __builtin_amdgcn_mfma_f32_16x16x32_bf16(ap, bv, acco[h][ct], 0, 0, 0);
                    }
                }
            }
            #pragma unroll
            for (int h = 0; h < 3; ++h)
                #pragma unroll
                for (int ct = 0; ct < 2; ++ct)
                    #pragma unroll
                    for (int r = 0; r < 4; ++r)
                        h2b[(wv * 16 + lk * 4 + r) * LDH + h * 32 + ct * 16 + lr] =
                            f2bf(acco[h][ct][r] * inv[h][r]);
        }

        // ---- P6: out-proj SWAPPED -> st float4 stores (own-wave 16 rows) ----
        float* st = (float*)U;   // overwrites pb: own-wave rows, program-ordered
        {
            bf16x8 o0 = *(const bf16x8*)&h2b[(wv * 16 + lr) * LDH +  0 + lk * 8];
            bf16x8 o1 = *(const bf16x8*)&h2b[(wv * 16 + lr) * LDH + 32 + lk * 8];
            bf16x8 o2 = *(const bf16x8*)&h2b[(wv * 16 + lr) * LDH + 64 + lk * 8];
            #pragma unroll
            for (int ct = 0; ct < 6; ++ct) {
                const short* bp = wob + (ct * 16 + lr) * 96 + lk * 8;
                bf16x8 b0 = *(const bf16x8*)(bp);
                bf16x8 b1 = *(const bf16x8*)(bp + 32);
                bf16x8 b2v = *(const bf16x8*)(bp + 64);
                f32x4 acc = (f32x4){0.f, 0.f, 0.f, 0.f};
                acc = __builtin_amdgcn_mfma_f32_16x16x32_bf16(b0, o0, acc, 0, 0, 0);
                acc = __builtin_amdgcn_mfma_f32_16x16x32_bf16(b1, o1, acc, 0, 0, 0);
                acc = __builtin_amdgcn_mfma_f32_16x16x32_bf16(b2v, o2, acc, 0, 0, 0);
                const float4 b4 = *(const float4*)&bo[ct * 16 + lk * 4];
                float4 v;
                v.x = acc[0] + b4.x; v.y = acc[1] + b4.y;
                v.z = acc[2] + b4.z; v.w = acc[3] + b4.w;
                *(float4*)&st[(wv * 16 + lr) * LDST + ct * 16 + lk * 4] = v;
            }
        }
        // No barrier: LN2 reads st rows [wv*16, wv*16+16) = own-wave rows.

        // ---- M1: LN2 from st (LDS), write h2b (own-wave rows). R12/R14
        //      arithmetic EXACT (sum order is numerics-critical, R13). ----
        {
            const int l = lt, p = lp;
            float s0 = 0.f, s1 = 0.f;
            #pragma unroll
            for (int c0 = 0; c0 < 24; ++c0) {
                float v = st[l * LDST + p * 24 + c0];
                s0 += v; s1 += v * v;
            }
            s0 += __shfl_xor(s0, 1); s1 += __shfl_xor(s1, 1);
            s0 += __shfl_xor(s0, 2); s1 += __shfl_xor(s1, 2);
            float mean = s0 * (1.f / 96.f);
            float var  = fmaxf(s1 * (1.f / 96.f) - mean * mean, 0.f);
            float rstd = rsqrtf(var + 1e-5f);
            #pragma unroll
            for (int c0 = 0; c0 < 24; ++c0) {
                int c = p * 24 + c0;
                float v = st[l * LDST + c];
                h2b[l * LDH + c] = f2bf((v - mean) * rstd * ln2w[c] + ln2b[c]);
            }
        }
        __syncthreads();   // h2b(LN2) + st complete; vt dead beyond here

        // ---- M2: MLP, swapped GEMMs, PING-PONG act buffers (vtact <-> h2b) --
        short* actQ0 = vtact;
        short* actQ1 = h2b;
        bf16x8 a1[4][3];
        #pragma unroll
        for (int rt = 0; rt < 4; ++rt)
            #pragma unroll
            for (int ks = 0; ks < 3; ++ks)
                a1[rt][ks] = *(const bf16x8*)&h2b[(rt * 16 + lr) * LDH + ks * 32 + lk * 8];

        f32x4 acc2[2][3];   // swapped: tok = wr*32+rt*16+lr, oc = wc*48+ct*16+lk*4+r
        #pragma unroll
        for (int rt = 0; rt < 2; ++rt)
            #pragma unroll
            for (int ct = 0; ct < 3; ++ct) acc2[rt][ct] = (f32x4){0.f, 0.f, 0.f, 0.f};

        for (int half = 0; half < 2; ++half) {
            const int oc0w = half * 192 + wv * 48;
            f32x4 acc1[4][3];   // swapped: tok = rt*16+lr, oc = oc0w+ct*16+lk*4+r
            #pragma unroll
            for (int rt = 0; rt < 4; ++rt)
                #pragma unroll
                for (int ct = 0; ct < 3; ++ct) acc1[rt][ct] = (f32x4){0.f, 0.f, 0.f, 0.f};

            #pragma unroll
            for (int ct = 0; ct < 3; ++ct) {
                const short* bp = w1b + (oc0w + ct * 16 + lr) * 96 + lk * 8;
                bf16x8 bg0 = *(const bf16x8*)(bp);
                bf16x8 bg1 = *(const bf16x8*)(bp + 32);
                bf16x8 bg2 = *(const bf16x8*)(bp + 64);
                #pragma unroll
                for (int rt = 0; rt < 4; ++rt) {
                    acc1[rt][ct] = __builtin_amdgcn_mfma_f32_16x16x32_bf16(bg0, a1[rt][0], acc1[rt][ct], 0, 0, 0);
                    acc1[rt][ct] = __builtin_amdgcn_mfma_f32_16x16x32_bf16(bg1, a1[rt][1], acc1[rt][ct], 0, 0, 0);
                    acc1[rt][ct] = __builtin_amdgcn_mfma_f32_16x16x32_bf16(bg2, a1[rt][2], acc1[rt][ct], 0, 0, 0);
                }
            }

            for (int sub = 0; sub < 2; ++sub) {
                short* actQ = (sub == 0) ? actQ0 : actQ1;   // ping-pong
                if (wr == sub) {
                    #pragma unroll
                    for (int ct = 0; ct < 3; ++ct) {
                        const float4 b14 = *(const float4*)&b1[oc0w + ct * 16 + lk * 4];
                        const int lcolb = wc * 48 + ct * 16 + lk * 4;
                        #pragma unroll
                        for (int rt = 0; rt < 4; ++rt) {
                            s16x4 pk;
                            pk[0] = f2bf(gelu_f(acc1[rt][ct][0] + b14.x));
                            pk[1] = f2bf(gelu_f(acc1[rt][ct][1] + b14.y));
                            pk[2] = f2bf(gelu_f(acc1[rt][ct][2] + b14.z));
                            pk[3] = f2bf(gelu_f(acc1[rt][ct][3] + b14.w));
                            *(s16x4*)&actQ[(rt * 16 + lr) * LDAQ + lcolb] = pk;
                        }
                    }
                }
                __syncthreads();           // actQ(quarter) ready

                #pragma unroll
                for (int ks = 0; ks < 3; ++ks) {
                    bf16x8 a2[2];
                    #pragma unroll
                    for (int rt = 0; rt < 2; ++rt)
                        a2[rt] = *(const bf16x8*)&actQ[(wr * 32 + rt * 16 + lr) * LDAQ + ks * 32 + lk * 8];
                    #pragma unroll
                    for (int ct = 0; ct < 3; ++ct) {
                        bf16x8 bw = *(const bf16x8*)(w2b + (wc * 48 + ct * 16 + lr) * 384
                                                      + half * 192 + sub * 96 + ks * 32 + lk * 8);
                        #pragma unroll
                        for (int rt = 0; rt < 2; ++rt)
                            acc2[rt][ct] = __builtin_amdgcn_mfma_f32_16x16x32_bf16(bw, a2[rt], acc2[rt][ct], 0, 0, 0);
                    }
                }
                // no trailing barrier (ping-pong; next quarter's ready-barrier
                // provides write-after-read ordering).
            }
        }

        // ---- M3: residual + bias into st, float4 RMW (disjoint 2x2 regions) --
        #pragma unroll
        for (int ct = 0; ct < 3; ++ct) {
            const int colb = wc * 48 + ct * 16 + lk * 4;
            const float4 b24 = *(const float4*)&b2[colb];
            #pragma unroll
            for (int rt = 0; rt < 2; ++rt) {
                const int row = wr * 32 + rt * 16 + lr;
                float4 v = *(const float4*)&st[row * LDST + colb];
                v.x += acc2[rt][ct][0] + b24.x;
                v.y += acc2[rt][ct][1] + b24.y;
                v.z += acc2[rt][ct][2] + b24.z;
                v.w += acc2[rt][ct][3] + b24.w;
                *(float4*)&st[row * LDST + colb] = v;
            }
        }
        __syncthreads();   // st complete for all waves

        // ---- P7: write-back ((lt,lp) map; un-roll cancels the roll) ----
        {
            const float* srow = &st[lt * LDST + lp * 24];
            float* orow = out + tb + lp * 24;
            #pragma unroll
            for (int jj = 0; jj < 6; ++jj)
                ((float4*)orow)[jj] = ((const float4*)srow)[jj];
        }
        __syncthreads();   // P7 reads done -> U free for next iteration's xf

        tb = tbn;
    }
}

// ---------------------------------------------------------------------------
extern "C" void kernel_launch(void* const* d_in, const int* in_sizes, int n_in,
                              void* d_out, int out_size, void* d_ws, size_t ws_size,
                              hipStream_t stream) {
    const float* x    = (const float*)d_in[0];
    const float* ln1w = (const float*)d_in[1];
    const float* ln1b = (const float*)d_in[2];
    const float* wqkv = (const float*)d_in[3];   // [288,96]
    const float* bqkv = (const float*)d_in[4];
    const float* wo   = (const float*)d_in[5];   // [96,96]
    const float* bo   = (const float*)d_in[6];
    const float* ln2w = (const float*)d_in[7];
    const float* ln2b = (const float*)d_in[8];
    const float* w1   = (const float*)d_in[9];   // [384,96]
    const float* b1   = (const float*)d_in[10];
    const float* w2   = (const float*)d_in[11];  // [96,384]
    const float* b2   = (const float*)d_in[12];
    float* out = (float*)d_out;

    short* ws  = (short*)d_ws;
    short* wqb = ws;            // 27648
    short* wob = ws + 27648;    // 9216
    short* w1b = ws + 36864;    // 36864
    short* w2b = ws + 73728;    // 36864   (total 221184 B)

    prep_bf16<<<432, 256, 0, stream>>>(wqkv, wo, w1, w2, ws);
    attn_mlp<<<GRID, 256, 0, stream>>>(x, ln1w, ln1b, wqb, bqkv, wob, bo,
                                       ln2w, ln2b, w1b, b1, w2b, b2, out);
}

// Round 16
// 187.744 us; speedup vs baseline: 2.0771x; 2.0771x over previous
//
#include <hip/hip_runtime.h>
#include <math.h>

// Problem constants (SwinBlock: B=4, H=W=224, C=96, WS=8, shift=4, NH=3, hd=32)
static constexpr int Hn   = 224;
static constexpr int Wn   = 224;
static constexpr int Cn   = 96;
static constexpr int Sft  = 4;     // WS/2
static constexpr int NWH  = 28;    // 224/8
static constexpr int NWPB = 784;   // 28*28
static constexpr int NW   = 3136;  // 4*784

typedef __attribute__((ext_vector_type(8))) short bf16x8;  // 8 bf16 in 4 VGPRs
typedef __attribute__((ext_vector_type(4))) float f32x4;
typedef __attribute__((ext_vector_type(4))) short s16x4;

// Native RNE float->bf16 (R11 win; 1 VALU op, rounding identical to manual RNE).
__device__ inline short f2bf(float f) {
    __bf16 h = (__bf16)f;
    return __builtin_bit_cast(short, h);
}

// Fast erf-based GELU (A&S 7.1.26, |eps_erf| <= 1.5e-7 -> invisible under the
// bf16 rounding that immediately follows).
__device__ inline float gelu_f(float a) {
    float u  = a * 0.70710678118654752f;
    float au = fabsf(u);
    float t  = __builtin_amdgcn_rcpf(fmaf(0.3275911f, au, 1.f));
    float e  = __expf(-u * u);
    float p  = t * fmaf(t, fmaf(t, fmaf(t, fmaf(t, 1.061405429f,
                        -1.453152027f), 1.421413741f), -0.284496736f),
                        0.254829592f);
    float er = fmaf(-p, e, 1.f);          // erf(|u|)
    er = (u < 0.f) ? -er : er;
    return 0.5f * a * (1.f + er);
}

// ---------------------------------------------------------------------------
// K0: convert ALL weights to bf16 into ws.
// layout (shorts): wqb[27648] | wob[9216] | w1b[36864] | w2b[36864]  (221184 B)
// ---------------------------------------------------------------------------
__global__ void prep_bf16(const float* __restrict__ wqkv, const float* __restrict__ wo,
                          const float* __restrict__ w1,   const float* __restrict__ w2,
                          short* __restrict__ ws) {
    int idx = blockIdx.x * 256 + threadIdx.x;
    if (idx < 27648)        ws[idx] = f2bf(wqkv[idx]);
    else if (idx < 36864)   ws[idx] = f2bf(wo[idx - 27648]);
    else if (idx < 73728)   ws[idx] = f2bf(w1[idx - 36864]);
    else if (idx < 110592)  ws[idx] = f2bf(w2[idx - 73728]);
}

// ---------------------------------------------------------------------------
// K1 (R16 = exact R14 revert — session best, 187.5 us): fused attn+mlp,
// 3 blocks/CU, per-window blocks.
// R15 post-mortem: persistent grid + cross-window register prefetch spilled
// (vpre live across the whole body; FETCH 39->474MB) — latency-hiding via
// persistence closed, same unified-register failure mode as R7/R9.
// Closed axes: occupancy (R7/R9 spills), barrier-free MLP (R10 load-amp),
// VALU thinning (R11/R12 kept, small), barrier count (R14 ~1%), LN sum-order
// (R13 numerics), persistence (R15 spills).
// Structure: swapped packed D-stores + native cvt + ping-pong act buffers.
// Sentinels: absmax == 9.766e-4 exactly, FETCH ~39MB.
// LDS unions:
//  U[25600]   : xf f32 -> Q|K bf16 -> P bf16 -> st f32 (lives to the end)
//  h2b[13312] : LN1-out -> O -> LN2-out -> actQ1 (ping-pong)
//  vtact[13824]: vt (V^T) -> actQ0
// Fragment layouts (mfma_f32_16x16x32_bf16, m89-verified):
//  A: row=lane&15, k=(lane>>4)*8+j ; B: col=lane&15, same k ;
//  D: col=lane&15, row=(lane>>4)*4+r   (swapped: transpose of this)
// ---------------------------------------------------------------------------
static constexpr int LDH  = 104;  // h2b stride (shorts)
static constexpr int LDQK = 200;  // U as Q|K: stride (shorts): Q[0..95] K[96..191] pad8
static constexpr int LDVT = 72;   // vt stride (shorts): [ch 96][tok 64 pad8]
static constexpr int LDP  = 200;  // U as P: [tok][h*64+kv] pad8 (shorts)
static constexpr int LDXF = 100;  // U as xf: stride (floats)
static constexpr int LDST = 100;  // U as st: stride (floats)
static constexpr int LDAQ = 104;  // actQ stride (shorts), one 96-col quarter (==LDH)

__global__ __launch_bounds__(256, 3) void attn_mlp(
    const float* __restrict__ x,
    const float* __restrict__ ln1w, const float* __restrict__ ln1b,
    const short* __restrict__ wqb,  const float* __restrict__ bqkv,
    const short* __restrict__ wob,  const float* __restrict__ bo,
    const float* __restrict__ ln2w, const float* __restrict__ ln2b,
    const short* __restrict__ w1b,  const float* __restrict__ b1,
    const short* __restrict__ w2b,  const float* __restrict__ b2,
    float* __restrict__ out)
{
    __shared__ __align__(16) char  U[64 * 400];        // xf -> Q|K -> P -> st
    __shared__ __align__(16) short h2b[64 * LDH];      // LN1 -> O -> LN2 -> actQ1
    __shared__ __align__(16) short vtact[96 * LDVT];   // vt -> actQ0
    __shared__ int   tbase[64];

    const int blk = blockIdx.x;
    const int b   = blk / NWPB;
    const int rem = blk - b * NWPB;
    const int wh  = rem / NWH;
    const int ww  = rem - wh * NWH;
    const int tid  = threadIdx.x;
    const int lane = tid & 63;
    const int wv   = __builtin_amdgcn_readfirstlane(tid >> 6);
    const int lr   = lane & 15;
    const int lk   = lane >> 4;
    const int wr   = wv >> 1;   // 2x2 wave split: row group (32 rows)
    const int wc   = wv & 1;    //                 col group

    if (tid < 64) {
        int i = tid >> 3, j = tid & 7;
        int hs = wh * 8 + i + Sft; if (hs >= Hn) hs -= Hn;
        int ws2 = ww * 8 + j + Sft; if (ws2 >= Wn) ws2 -= Wn;
        tbase[tid] = ((b * Hn + hs) * Wn + ws2) * Cn;
    }
    __syncthreads();

    // ---- P1: load x [64][96] (float4, 16B-aligned rows) into U as xf ----
    float* xf = (float*)U;
    for (int i = tid; i < 64 * 24; i += 256) {
        int row = i / 24, c4 = i - row * 24;
        float4 v = ((const float4*)(x + tbase[row]))[c4];
        *(float4*)&xf[row * LDXF + c4 * 4] = v;
    }
    __syncthreads();

    // ---- P2: LN1 (4 lanes/token) ----
    {
        const int l = tid >> 2, p = tid & 3;
        float s0 = 0.f, s1 = 0.f;
        #pragma unroll
        for (int c0 = 0; c0 < 24; ++c0) {
            float v = xf[l * LDXF + p * 24 + c0];
            s0 += v; s1 += v * v;
        }
        s0 += __shfl_xor(s0, 1); s1 += __shfl_xor(s1, 1);
        s0 += __shfl_xor(s0, 2); s1 += __shfl_xor(s1, 2);
        float mean = s0 * (1.f / 96.f);
        float var  = fmaxf(s1 * (1.f / 96.f) - mean * mean, 0.f);
        float rstd = rsqrtf(var + 1e-5f);
        #pragma unroll
        for (int c0 = 0; c0 < 24; ++c0) {
            int c = p * 24 + c0;
            float v = xf[l * LDXF + c];
            h2b[l * LDH + c] = f2bf((v - mean) * rstd * ln1w[c] + ln1b[c]);
        }
    }
    __syncthreads();   // h2b ready; xf dead (fences Q/K overwrite)

    // ---- P3: QKV GEMM, 2x2 split. Q/K: SWAPPED mfma -> packed s16x4 row
    //      stores. V: unswapped (packs into transposed vt). ----
    short* qk = (short*)U;
    short* vt = vtact;
    {
        bf16x8 aq[2][3];
        #pragma unroll
        for (int rt = 0; rt < 2; ++rt)
            #pragma unroll
            for (int ks = 0; ks < 3; ++ks)
                aq[rt][ks] = *(const bf16x8*)&h2b[(wr * 32 + rt * 16 + lr) * LDH + ks * 32 + lk * 8];

        #pragma unroll 3
        for (int ct9 = 0; ct9 < 9; ++ct9) {
            const int ct = wc * 9 + ct9;
            const short* bp = wqb + (ct * 16 + lr) * 96 + lk * 8;
            bf16x8 b0 = *(const bf16x8*)(bp);
            bf16x8 b1 = *(const bf16x8*)(bp + 32);
            bf16x8 b2v = *(const bf16x8*)(bp + 64);
            if (ct < 12) {               // Q,K: swapped -> D^T, packed store
                const float4 b4 = *(const float4*)&bqkv[ct * 16 + lk * 4];
                #pragma unroll
                for (int rt = 0; rt < 2; ++rt) {
                    f32x4 acc = (f32x4){0.f, 0.f, 0.f, 0.f};
                    acc = __builtin_amdgcn_mfma_f32_16x16x32_bf16(b0, aq[rt][0], acc, 0, 0, 0);
                    acc = __builtin_amdgcn_mfma_f32_16x16x32_bf16(b1, aq[rt][1], acc, 0, 0, 0);
                    acc = __builtin_amdgcn_mfma_f32_16x16x32_bf16(b2v, aq[rt][2], acc, 0, 0, 0);
                    const int tok = wr * 32 + rt * 16 + lr;
                    s16x4 pk;
                    pk[0] = f2bf(acc[0] + b4.x); pk[1] = f2bf(acc[1] + b4.y);
                    pk[2] = f2bf(acc[2] + b4.z); pk[3] = f2bf(acc[3] + b4.w);
                    *(s16x4*)&qk[tok * LDQK + ct * 16 + lk * 4] = pk;
                }
            } else {                     // V: unswapped -> transposed vt store
                const float bs = bqkv[ct * 16 + lr];
                #pragma unroll
                for (int rt = 0; rt < 2; ++rt) {
                    f32x4 acc = (f32x4){0.f, 0.f, 0.f, 0.f};
                    acc = __builtin_amdgcn_mfma_f32_16x16x32_bf16(aq[rt][0], b0, acc, 0, 0, 0);
                    acc = __builtin_amdgcn_mfma_f32_16x16x32_bf16(aq[rt][1], b1, acc, 0, 0, 0);
                    acc = __builtin_amdgcn_mfma_f32_16x16x32_bf16(aq[rt][2], b2v, acc, 0, 0, 0);
                    const int rb = wr * 32 + rt * 16;
                    s16x4 pk;
                    #pragma unroll
                    for (int r = 0; r < 4; ++r) pk[r] = f2bf(acc[r] + bs);
                    *(s16x4*)&vt[(ct * 16 + lr - 192) * LDVT + rb + lk * 4] = pk;
                }
            }
        }
    }
    __syncthreads();   // Q,K,V visible to all waves

    // ---- P4: S = QK^T per head (wave -> query row-tile wv), softmax ----
    short* pb = (short*)U;   // P overwrites Q|K after the barrier below
    {
        f32x4 accs[3][4];
        #pragma unroll
        for (int h = 0; h < 3; ++h) {
            bf16x8 aqf = *(const bf16x8*)&qk[(wv * 16 + lr) * LDQK + h * 32 + lk * 8];
            #pragma unroll
            for (int ct = 0; ct < 4; ++ct) {
                bf16x8 bk = *(const bf16x8*)&qk[(ct * 16 + lr) * LDQK + 96 + h * 32 + lk * 8];
                f32x4 z = (f32x4){0.f, 0.f, 0.f, 0.f};
                accs[h][ct] = __builtin_amdgcn_mfma_f32_16x16x32_bf16(aqf, bk, z, 0, 0, 0);
            }
        }
        __syncthreads();   // every wave done reading K -> P may overwrite U

        const float scale = 0.17677669529663687f;  // 1/sqrt(32)
        float inv[3][4];
        #pragma unroll
        for (int h = 0; h < 3; ++h) {
            #pragma unroll
            for (int r = 0; r < 4; ++r) {
                float m = fmaxf(fmaxf(accs[h][0][r], accs[h][1][r]),
                                fmaxf(accs[h][2][r], accs[h][3][r]));
                m = fmaxf(m, __shfl_xor(m, 1));
                m = fmaxf(m, __shfl_xor(m, 2));
                m = fmaxf(m, __shfl_xor(m, 4));
                m = fmaxf(m, __shfl_xor(m, 8));
                float s = 0.f;
                #pragma unroll
                for (int ct = 0; ct < 4; ++ct) {
                    float p = __expf((accs[h][ct][r] - m) * scale);
                    accs[h][ct][r] = p; s += p;
                }
                s += __shfl_xor(s, 1); s += __shfl_xor(s, 2);
                s += __shfl_xor(s, 4); s += __shfl_xor(s, 8);
                inv[h][r] = 1.f / s;
            }
        }
        // P -> bf16 LDS (rows of own wave only; no barrier needed)
        #pragma unroll
        for (int h = 0; h < 3; ++h)
            #pragma unroll
            for (int ct = 0; ct < 4; ++ct)
                #pragma unroll
                for (int r = 0; r < 4; ++r)
                    pb[(wv * 16 + lk * 4 + r) * LDP + h * 64 + ct * 16 + lr] =
                        f2bf(accs[h][ct][r]);

        // ---- P5: O = P V (deferred 1/sum), write O bf16 into h2b ----
        f32x4 acco[3][2];
        #pragma unroll
        for (int h = 0; h < 3; ++h)
            #pragma unroll
            for (int ct = 0; ct < 2; ++ct) acco[h][ct] = (f32x4){0.f, 0.f, 0.f, 0.f};
        #pragma unroll
        for (int h = 0; h < 3; ++h) {
            #pragma unroll
            for (int ks = 0; ks < 2; ++ks) {
                bf16x8 ap = *(const bf16x8*)&pb[(wv * 16 + lr) * LDP + h * 64 + ks * 32 + lk * 8];
                #pragma unroll
                for (int ct = 0; ct < 2; ++ct) {
                    bf16x8 bv = *(const bf16x8*)&vt[(h * 32 + ct * 16 + lr) * LDVT + ks * 32 + lk * 8];
                    acco[h][ct] = __builtin_amdgcn_mfma_f32_16x16x32_bf16(ap, bv, acco[h][ct], 0, 0, 0);
                }
            }
        }
        #pragma unroll
        for (int h = 0; h < 3; ++h)
            #pragma unroll
            for (int ct = 0; ct < 2; ++ct)
                #pragma unroll
                for (int r = 0; r < 4; ++r)
                    h2b[(wv * 16 + lk * 4 + r) * LDH + h * 32 + ct * 16 + lr] =
                        f2bf(acco[h][ct][r] * inv[h][r]);
    }

    // ---- P6: out-proj SWAPPED -> st float4 stores (own-wave 16 rows) ----
    float* st = (float*)U;   // overwrites pb: own-wave rows, program-ordered
    {
        bf16x8 o0 = *(const bf16x8*)&h2b[(wv * 16 + lr) * LDH +  0 + lk * 8];
        bf16x8 o1 = *(const bf16x8*)&h2b[(wv * 16 + lr) * LDH + 32 + lk * 8];
        bf16x8 o2 = *(const bf16x8*)&h2b[(wv * 16 + lr) * LDH + 64 + lk * 8];
        #pragma unroll
        for (int ct = 0; ct < 6; ++ct) {
            const short* bp = wob + (ct * 16 + lr) * 96 + lk * 8;
            bf16x8 b0 = *(const bf16x8*)(bp);
            bf16x8 b1 = *(const bf16x8*)(bp + 32);
            bf16x8 b2v = *(const bf16x8*)(bp + 64);
            f32x4 acc = (f32x4){0.f, 0.f, 0.f, 0.f};
            acc = __builtin_amdgcn_mfma_f32_16x16x32_bf16(b0, o0, acc, 0, 0, 0);
            acc = __builtin_amdgcn_mfma_f32_16x16x32_bf16(b1, o1, acc, 0, 0, 0);
            acc = __builtin_amdgcn_mfma_f32_16x16x32_bf16(b2v, o2, acc, 0, 0, 0);
            const float4 b4 = *(const float4*)&bo[ct * 16 + lk * 4];
            float4 v;
            v.x = acc[0] + b4.x; v.y = acc[1] + b4.y;
            v.z = acc[2] + b4.z; v.w = acc[3] + b4.w;
            *(float4*)&st[(wv * 16 + lr) * LDST + ct * 16 + lk * 4] = v;
        }
    }
    // No barrier: LN2 reads st rows [wv*16, wv*16+16) = own-wave rows.

    // ---- M1: LN2 from st (LDS), write h2b (own-wave rows). R12 arithmetic
    //      EXACT (contiguous 24-sum + xor1/2; sum order numerics-critical). ----
    {
        const int l = tid >> 2, p = tid & 3;
        float s0 = 0.f, s1 = 0.f;
        #pragma unroll
        for (int c0 = 0; c0 < 24; ++c0) {
            float v = st[l * LDST + p * 24 + c0];
            s0 += v; s1 += v * v;
        }
        s0 += __shfl_xor(s0, 1); s1 += __shfl_xor(s1, 1);
        s0 += __shfl_xor(s0, 2); s1 += __shfl_xor(s1, 2);
        float mean = s0 * (1.f / 96.f);
        float var  = fmaxf(s1 * (1.f / 96.f) - mean * mean, 0.f);
        float rstd = rsqrtf(var + 1e-5f);
        #pragma unroll
        for (int c0 = 0; c0 < 24; ++c0) {
            int c = p * 24 + c0;
            float v = st[l * LDST + c];
            h2b[l * LDH + c] = f2bf((v - mean) * rstd * ln2w[c] + ln2b[c]);
        }
    }
    __syncthreads();   // h2b(LN2) + st complete; vt dead beyond here

    // ---- M2: MLP, swapped GEMMs, PING-PONG act buffers (vtact <-> h2b).
    //      a1 frags loaded BEFORE the loop; their lgkm drain happens at the
    //      first ready-barrier (h0,s0) -> first h2b-act write at (h0,s1) is
    //      safe. Buffer rewrite at step i+2 fenced by step-i+1 barrier. ----
    short* actQ0 = vtact;
    short* actQ1 = h2b;
    bf16x8 a1[4][3];
    #pragma unroll
    for (int rt = 0; rt < 4; ++rt)
        #pragma unroll
        for (int ks = 0; ks < 3; ++ks)
            a1[rt][ks] = *(const bf16x8*)&h2b[(rt * 16 + lr) * LDH + ks * 32 + lk * 8];

    f32x4 acc2[2][3];   // swapped: tok = wr*32+rt*16+lr, oc = wc*48+ct*16+lk*4+r
    #pragma unroll
    for (int rt = 0; rt < 2; ++rt)
        #pragma unroll
        for (int ct = 0; ct < 3; ++ct) acc2[rt][ct] = (f32x4){0.f, 0.f, 0.f, 0.f};

    for (int half = 0; half < 2; ++half) {
        const int oc0w = half * 192 + wv * 48;
        f32x4 acc1[4][3];   // swapped: tok = rt*16+lr, oc = oc0w+ct*16+lk*4+r
        #pragma unroll
        for (int rt = 0; rt < 4; ++rt)
            #pragma unroll
            for (int ct = 0; ct < 3; ++ct) acc1[rt][ct] = (f32x4){0.f, 0.f, 0.f, 0.f};

        #pragma unroll
        for (int ct = 0; ct < 3; ++ct) {
            const short* bp = w1b + (oc0w + ct * 16 + lr) * 96 + lk * 8;
            bf16x8 bg0 = *(const bf16x8*)(bp);
            bf16x8 bg1 = *(const bf16x8*)(bp + 32);
            bf16x8 bg2 = *(const bf16x8*)(bp + 64);
            #pragma unroll
            for (int rt = 0; rt < 4; ++rt) {
                acc1[rt][ct] = __builtin_amdgcn_mfma_f32_16x16x32_bf16(bg0, a1[rt][0], acc1[rt][ct], 0, 0, 0);
                acc1[rt][ct] = __builtin_amdgcn_mfma_f32_16x16x32_bf16(bg1, a1[rt][1], acc1[rt][ct], 0, 0, 0);
                acc1[rt][ct] = __builtin_amdgcn_mfma_f32_16x16x32_bf16(bg2, a1[rt][2], acc1[rt][ct], 0, 0, 0);
            }
        }

        for (int sub = 0; sub < 2; ++sub) {
            short* actQ = (sub == 0) ? actQ0 : actQ1;   // ping-pong
            // waves whose 48 cols fall in quarter `sub` write act (bias+GELU)
            if (wr == sub) {
                #pragma unroll
                for (int ct = 0; ct < 3; ++ct) {
                    const float4 b14 = *(const float4*)&b1[oc0w + ct * 16 + lk * 4];
                    const int lcolb = wc * 48 + ct * 16 + lk * 4;  // col within quarter
                    #pragma unroll
                    for (int rt = 0; rt < 4; ++rt) {
                        s16x4 pk;
                        pk[0] = f2bf(gelu_f(acc1[rt][ct][0] + b14.x));
                        pk[1] = f2bf(gelu_f(acc1[rt][ct][1] + b14.y));
                        pk[2] = f2bf(gelu_f(acc1[rt][ct][2] + b14.z));
                        pk[3] = f2bf(gelu_f(acc1[rt][ct][3] + b14.w));
                        *(s16x4*)&actQ[(rt * 16 + lr) * LDAQ + lcolb] = pk;
                    }
                }
            }
            __syncthreads();           // actQ(quarter) ready (drains lgkm/writes)

            // GEMM2 slice: k = half*192 + sub*96 .. +96 (swapped)
            #pragma unroll
            for (int ks = 0; ks < 3; ++ks) {
                bf16x8 a2[2];
                #pragma unroll
                for (int rt = 0; rt < 2; ++rt)
                    a2[rt] = *(const bf16x8*)&actQ[(wr * 32 + rt * 16 + lr) * LDAQ + ks * 32 + lk * 8];
                #pragma unroll
                for (int ct = 0; ct < 3; ++ct) {
                    bf16x8 bw = *(const bf16x8*)(w2b + (wc * 48 + ct * 16 + lr) * 384
                                                  + half * 192 + sub * 96 + ks * 32 + lk * 8);
                    #pragma unroll
                    for (int rt = 0; rt < 2; ++rt)
                        acc2[rt][ct] = __builtin_amdgcn_mfma_f32_16x16x32_bf16(bw, a2[rt], acc2[rt][ct], 0, 0, 0);
                }
            }
            // no trailing barrier: next quarter uses the OTHER buffer; its
            // ready-barrier provides the write-after-read ordering.
        }
    }

    // ---- M3: residual + bias into st, float4 RMW (disjoint 2x2 regions).
    //      All st writes (P6) precede the pre-M2 barrier -> RMW safe. ----
    #pragma unroll
    for (int ct = 0; ct < 3; ++ct) {
        const int colb = wc * 48 + ct * 16 + lk * 4;
        const float4 b24 = *(const float4*)&b2[colb];
        #pragma unroll
        for (int rt = 0; rt < 2; ++rt) {
            const int row = wr * 32 + rt * 16 + lr;
            float4 v = *(const float4*)&st[row * LDST + colb];
            v.x += acc2[rt][ct][0] + b24.x;
            v.y += acc2[rt][ct][1] + b24.y;
            v.z += acc2[rt][ct][2] + b24.z;
            v.w += acc2[rt][ct][3] + b24.w;
            *(float4*)&st[row * LDST + colb] = v;
        }
    }
    __syncthreads();

    // ---- P7: coalesced write-back; un-roll cancels the roll ----
    for (int i = tid; i < 64 * 96; i += 256) {
        int l = i / 96, c = i - l * 96;
        out[tbase[l] + c] = st[l * LDST + c];
    }
}

// ---------------------------------------------------------------------------
extern "C" void kernel_launch(void* const* d_in, const int* in_sizes, int n_in,
                              void* d_out, int out_size, void* d_ws, size_t ws_size,
                              hipStream_t stream) {
    const float* x    = (const float*)d_in[0];
    const float* ln1w = (const float*)d_in[1];
    const float* ln1b = (const float*)d_in[2];
    const float* wqkv = (const float*)d_in[3];   // [288,96]
    const float* bqkv = (const float*)d_in[4];
    const float* wo   = (const float*)d_in[5];   // [96,96]
    const float* bo   = (const float*)d_in[6];
    const float* ln2w = (const float*)d_in[7];
    const float* ln2b = (const float*)d_in[8];
    const float* w1   = (const float*)d_in[9];   // [384,96]
    const float* b1   = (const float*)d_in[10];
    const float* w2   = (const float*)d_in[11];  // [96,384]
    const float* b2   = (const float*)d_in[12];
    float* out = (float*)d_out;

    short* ws  = (short*)d_ws;
    short* wqb = ws;            // 27648
    short* wob = ws + 27648;    // 9216
    short* w1b = ws + 36864;    // 36864
    short* w2b = ws + 73728;    // 36864   (total 221184 B)

    prep_bf16<<<432, 256, 0, stream>>>(wqkv, wo, w1, w2, ws);
    attn_mlp<<<NW, 256, 0, stream>>>(x, ln1w, ln1b, wqb, bqkv, wob, bo,
                                     ln2w, ln2b, w1b, b1, w2b, b2, out);
}

// Round 17
// 184.231 us; speedup vs baseline: 2.1167x; 1.0191x over previous
//
#include <hip/hip_runtime.h>
#include <math.h>

// Problem constants (SwinBlock: B=4, H=W=224, C=96, WS=8, shift=4, NH=3, hd=32)
static constexpr int Hn   = 224;
static constexpr int Wn   = 224;
static constexpr int Cn   = 96;
static constexpr int Sft  = 4;     // WS/2
static constexpr int NWH  = 28;    // 224/8
static constexpr int NWPB = 784;   // 28*28
static constexpr int NW   = 3136;  // 4*784

typedef __attribute__((ext_vector_type(8))) short bf16x8;  // 8 bf16 in 4 VGPRs
typedef __attribute__((ext_vector_type(4))) float f32x4;
typedef __attribute__((ext_vector_type(4))) short s16x4;

// Native RNE float->bf16 (R11 win; 1 VALU op, rounding identical to manual RNE).
__device__ inline short f2bf(float f) {
    __bf16 h = (__bf16)f;
    return __builtin_bit_cast(short, h);
}

// Fast erf-based GELU (A&S 7.1.26, |eps_erf| <= 1.5e-7 -> invisible under the
// bf16 rounding that immediately follows).
__device__ inline float gelu_f(float a) {
    float u  = a * 0.70710678118654752f;
    float au = fabsf(u);
    float t  = __builtin_amdgcn_rcpf(fmaf(0.3275911f, au, 1.f));
    float e  = __expf(-u * u);
    float p  = t * fmaf(t, fmaf(t, fmaf(t, fmaf(t, 1.061405429f,
                        -1.453152027f), 1.421413741f), -0.284496736f),
                        0.254829592f);
    float er = fmaf(-p, e, 1.f);          // erf(|u|)
    er = (u < 0.f) ? -er : er;
    return 0.5f * a * (1.f + er);
}

// ---------------------------------------------------------------------------
// K0: convert ALL weights to bf16 into ws.
// layout (shorts): wqb[27648] | wob[9216] | w1b[36864] | w2b[36864]  (221184 B)
// ---------------------------------------------------------------------------
__global__ void prep_bf16(const float* __restrict__ wqkv, const float* __restrict__ wo,
                          const float* __restrict__ w1,   const float* __restrict__ w2,
                          short* __restrict__ ws) {
    int idx = blockIdx.x * 256 + threadIdx.x;
    if (idx < 27648)        ws[idx] = f2bf(wqkv[idx]);
    else if (idx < 36864)   ws[idx] = f2bf(wo[idx - 27648]);
    else if (idx < 73728)   ws[idx] = f2bf(w1[idx - 36864]);
    else if (idx < 110592)  ws[idx] = f2bf(w2[idx - 73728]);
}

// ---------------------------------------------------------------------------
// K1 (R17 = R16 − xf/tbase staging): fused attn+mlp, 3 blocks/CU.
// xf's ONLY consumer is LN1 (attention replaces x; no residual use of x), so
// P1 + tbase are pure overhead: each thread now computes its own tb, loads
// its 24 x-values global->registers (6x float4, SAME addresses/order ->
// bit-identical LN1 sums), and LN1 runs from registers. P7 uses the
// R15-PROVEN (lt,lp) float4 map with the same per-thread tb (1 live VGPR —
// not R15's 24, no spill). Barriers 11 -> 9; ~48 LDS ops/thread removed.
// This also isolates the last untested R4-suspect (LN1-from-global): R5
// failed WITHOUT it, R15 passed bit-exact with per-thread decode + (lt,lp)
// P7 — if this fails ~6e-3, LN1-from-global is convicted and blacklisted.
// Sentinels: absmax == 9.766e-4 EXACTLY (identical arithmetic), FETCH ~39MB.
// LDS unions:
//  U[25600]   : Q|K bf16 -> P bf16 -> st f32 (lives to the end)
//  h2b[13312] : LN1-out -> O -> LN2-out -> actQ1 (ping-pong)
//  vtact[13824]: vt (V^T) -> actQ0
// Fragment layouts (mfma_f32_16x16x32_bf16, m89-verified):
//  A: row=lane&15, k=(lane>>4)*8+j ; B: col=lane&15, same k ;
//  D: col=lane&15, row=(lane>>4)*4+r   (swapped: transpose of this)
// ---------------------------------------------------------------------------
static constexpr int LDH  = 104;  // h2b stride (shorts)
static constexpr int LDQK = 200;  // U as Q|K: stride (shorts): Q[0..95] K[96..191] pad8
static constexpr int LDVT = 72;   // vt stride (shorts): [ch 96][tok 64 pad8]
static constexpr int LDP  = 200;  // U as P: [tok][h*64+kv] pad8 (shorts)
static constexpr int LDST = 100;  // U as st: stride (floats)
static constexpr int LDAQ = 104;  // actQ stride (shorts), one 96-col quarter (==LDH)

__global__ __launch_bounds__(256, 3) void attn_mlp(
    const float* __restrict__ x,
    const float* __restrict__ ln1w, const float* __restrict__ ln1b,
    const short* __restrict__ wqb,  const float* __restrict__ bqkv,
    const short* __restrict__ wob,  const float* __restrict__ bo,
    const float* __restrict__ ln2w, const float* __restrict__ ln2b,
    const short* __restrict__ w1b,  const float* __restrict__ b1,
    const short* __restrict__ w2b,  const float* __restrict__ b2,
    float* __restrict__ out)
{
    __shared__ __align__(16) char  U[64 * 400];        // Q|K -> P -> st
    __shared__ __align__(16) short h2b[64 * LDH];      // LN1 -> O -> LN2 -> actQ1
    __shared__ __align__(16) short vtact[96 * LDVT];   // vt -> actQ0

    const int blk = blockIdx.x;
    const int b   = blk / NWPB;
    const int rem = blk - b * NWPB;
    const int wh  = rem / NWH;
    const int ww  = rem - wh * NWH;
    const int tid  = threadIdx.x;
    const int lane = tid & 63;
    const int wv   = __builtin_amdgcn_readfirstlane(tid >> 6);
    const int lr   = lane & 15;
    const int lk   = lane >> 4;
    const int wr   = wv >> 1;   // 2x2 wave split: row group (32 rows)
    const int wc   = wv & 1;    //                 col group
    const int lt   = tid >> 2;  // token row this thread owns (LN1/LN2/P7)
    const int lp   = tid & 3;   // quarter (24 cols)

    // per-thread shifted/rolled global row base for token lt (replaces tbase)
    int tb;
    {
        const int ti = lt >> 3, tj = lt & 7;
        int hs  = wh * 8 + ti + Sft; if (hs  >= Hn) hs  -= Hn;
        int ws2 = ww * 8 + tj + Sft; if (ws2 >= Wn) ws2 -= Wn;
        tb = ((b * Hn + hs) * Wn + ws2) * Cn;
    }

    // ---- P2: LN1 straight from global x (registers). Loads/sums/stores are
    //      value- and order-identical to R16's xf-staged version. ----
    {
        float v[24];
        const float4* xp = (const float4*)(x + tb + lp * 24);
        #pragma unroll
        for (int jj = 0; jj < 6; ++jj) {
            float4 t = xp[jj];
            v[4*jj+0] = t.x; v[4*jj+1] = t.y; v[4*jj+2] = t.z; v[4*jj+3] = t.w;
        }
        float s0 = 0.f, s1 = 0.f;
        #pragma unroll
        for (int c0 = 0; c0 < 24; ++c0) { s0 += v[c0]; s1 += v[c0] * v[c0]; }
        s0 += __shfl_xor(s0, 1); s1 += __shfl_xor(s1, 1);
        s0 += __shfl_xor(s0, 2); s1 += __shfl_xor(s1, 2);
        float mean = s0 * (1.f / 96.f);
        float var  = fmaxf(s1 * (1.f / 96.f) - mean * mean, 0.f);
        float rstd = rsqrtf(var + 1e-5f);
        #pragma unroll
        for (int c0 = 0; c0 < 24; ++c0) {
            int c = lp * 24 + c0;
            h2b[lt * LDH + c] = f2bf((v[c0] - mean) * rstd * ln1w[c] + ln1b[c]);
        }
    }
    __syncthreads();   // h2b ready for all waves (P3 reads cross-wave rows)

    // ---- P3: QKV GEMM, 2x2 split. Q/K: SWAPPED mfma -> packed s16x4 row
    //      stores. V: unswapped (packs into transposed vt). ----
    short* qk = (short*)U;
    short* vt = vtact;
    {
        bf16x8 aq[2][3];
        #pragma unroll
        for (int rt = 0; rt < 2; ++rt)
            #pragma unroll
            for (int ks = 0; ks < 3; ++ks)
                aq[rt][ks] = *(const bf16x8*)&h2b[(wr * 32 + rt * 16 + lr) * LDH + ks * 32 + lk * 8];

        #pragma unroll 3
        for (int ct9 = 0; ct9 < 9; ++ct9) {
            const int ct = wc * 9 + ct9;
            const short* bp = wqb + (ct * 16 + lr) * 96 + lk * 8;
            bf16x8 b0 = *(const bf16x8*)(bp);
            bf16x8 b1 = *(const bf16x8*)(bp + 32);
            bf16x8 b2v = *(const bf16x8*)(bp + 64);
            if (ct < 12) {               // Q,K: swapped -> D^T, packed store
                const float4 b4 = *(const float4*)&bqkv[ct * 16 + lk * 4];
                #pragma unroll
                for (int rt = 0; rt < 2; ++rt) {
                    f32x4 acc = (f32x4){0.f, 0.f, 0.f, 0.f};
                    acc = __builtin_amdgcn_mfma_f32_16x16x32_bf16(b0, aq[rt][0], acc, 0, 0, 0);
                    acc = __builtin_amdgcn_mfma_f32_16x16x32_bf16(b1, aq[rt][1], acc, 0, 0, 0);
                    acc = __builtin_amdgcn_mfma_f32_16x16x32_bf16(b2v, aq[rt][2], acc, 0, 0, 0);
                    const int tok = wr * 32 + rt * 16 + lr;
                    s16x4 pk;
                    pk[0] = f2bf(acc[0] + b4.x); pk[1] = f2bf(acc[1] + b4.y);
                    pk[2] = f2bf(acc[2] + b4.z); pk[3] = f2bf(acc[3] + b4.w);
                    *(s16x4*)&qk[tok * LDQK + ct * 16 + lk * 4] = pk;
                }
            } else {                     // V: unswapped -> transposed vt store
                const float bs = bqkv[ct * 16 + lr];
                #pragma unroll
                for (int rt = 0; rt < 2; ++rt) {
                    f32x4 acc = (f32x4){0.f, 0.f, 0.f, 0.f};
                    acc = __builtin_amdgcn_mfma_f32_16x16x32_bf16(aq[rt][0], b0, acc, 0, 0, 0);
                    acc = __builtin_amdgcn_mfma_f32_16x16x32_bf16(aq[rt][1], b1, acc, 0, 0, 0);
                    acc = __builtin_amdgcn_mfma_f32_16x16x32_bf16(aq[rt][2], b2v, acc, 0, 0, 0);
                    const int rb = wr * 32 + rt * 16;
                    s16x4 pk;
                    #pragma unroll
                    for (int r = 0; r < 4; ++r) pk[r] = f2bf(acc[r] + bs);
                    *(s16x4*)&vt[(ct * 16 + lr - 192) * LDVT + rb + lk * 4] = pk;
                }
            }
        }
    }
    __syncthreads();   // Q,K,V visible to all waves

    // ---- P4: S = QK^T per head (wave -> query row-tile wv), softmax ----
    short* pb = (short*)U;   // P overwrites Q|K after the barrier below
    {
        f32x4 accs[3][4];
        #pragma unroll
        for (int h = 0; h < 3; ++h) {
            bf16x8 aqf = *(const bf16x8*)&qk[(wv * 16 + lr) * LDQK + h * 32 + lk * 8];
            #pragma unroll
            for (int ct = 0; ct < 4; ++ct) {
                bf16x8 bk = *(const bf16x8*)&qk[(ct * 16 + lr) * LDQK + 96 + h * 32 + lk * 8];
                f32x4 z = (f32x4){0.f, 0.f, 0.f, 0.f};
                accs[h][ct] = __builtin_amdgcn_mfma_f32_16x16x32_bf16(aqf, bk, z, 0, 0, 0);
            }
        }
        __syncthreads();   // every wave done reading K -> P may overwrite U

        const float scale = 0.17677669529663687f;  // 1/sqrt(32)
        float inv[3][4];
        #pragma unroll
        for (int h = 0; h < 3; ++h) {
            #pragma unroll
            for (int r = 0; r < 4; ++r) {
                float m = fmaxf(fmaxf(accs[h][0][r], accs[h][1][r]),
                                fmaxf(accs[h][2][r], accs[h][3][r]));
                m = fmaxf(m, __shfl_xor(m, 1));
                m = fmaxf(m, __shfl_xor(m, 2));
                m = fmaxf(m, __shfl_xor(m, 4));
                m = fmaxf(m, __shfl_xor(m, 8));
                float s = 0.f;
                #pragma unroll
                for (int ct = 0; ct < 4; ++ct) {
                    float p = __expf((accs[h][ct][r] - m) * scale);
                    accs[h][ct][r] = p; s += p;
                }
                s += __shfl_xor(s, 1); s += __shfl_xor(s, 2);
                s += __shfl_xor(s, 4); s += __shfl_xor(s, 8);
                inv[h][r] = 1.f / s;
            }
        }
        // P -> bf16 LDS (rows of own wave only; no barrier needed)
        #pragma unroll
        for (int h = 0; h < 3; ++h)
            #pragma unroll
            for (int ct = 0; ct < 4; ++ct)
                #pragma unroll
                for (int r = 0; r < 4; ++r)
                    pb[(wv * 16 + lk * 4 + r) * LDP + h * 64 + ct * 16 + lr] =
                        f2bf(accs[h][ct][r]);

        // ---- P5: O = P V (deferred 1/sum), write O bf16 into h2b ----
        f32x4 acco[3][2];
        #pragma unroll
        for (int h = 0; h < 3; ++h)
            #pragma unroll
            for (int ct = 0; ct < 2; ++ct) acco[h][ct] = (f32x4){0.f, 0.f, 0.f, 0.f};
        #pragma unroll
        for (int h = 0; h < 3; ++h) {
            #pragma unroll
            for (int ks = 0; ks < 2; ++ks) {
                bf16x8 ap = *(const bf16x8*)&pb[(wv * 16 + lr) * LDP + h * 64 + ks * 32 + lk * 8];
                #pragma unroll
                for (int ct = 0; ct < 2; ++ct) {
                    bf16x8 bv = *(const bf16x8*)&vt[(h * 32 + ct * 16 + lr) * LDVT + ks * 32 + lk * 8];
                    acco[h][ct] = __builtin_amdgcn_mfma_f32_16x16x32_bf16(ap, bv, acco[h][ct], 0, 0, 0);
                }
            }
        }
        #pragma unroll
        for (int h = 0; h < 3; ++h)
            #pragma unroll
            for (int ct = 0; ct < 2; ++ct)
                #pragma unroll
                for (int r = 0; r < 4; ++r)
                    h2b[(wv * 16 + lk * 4 + r) * LDH + h * 32 + ct * 16 + lr] =
                        f2bf(acco[h][ct][r] * inv[h][r]);
    }

    // ---- P6: out-proj SWAPPED -> st float4 stores (own-wave 16 rows) ----
    float* st = (float*)U;   // overwrites pb: own-wave rows, program-ordered
    {
        bf16x8 o0 = *(const bf16x8*)&h2b[(wv * 16 + lr) * LDH +  0 + lk * 8];
        bf16x8 o1 = *(const bf16x8*)&h2b[(wv * 16 + lr) * LDH + 32 + lk * 8];
        bf16x8 o2 = *(const bf16x8*)&h2b[(wv * 16 + lr) * LDH + 64 + lk * 8];
        #pragma unroll
        for (int ct = 0; ct < 6; ++ct) {
            const short* bp = wob + (ct * 16 + lr) * 96 + lk * 8;
            bf16x8 b0 = *(const bf16x8*)(bp);
            bf16x8 b1 = *(const bf16x8*)(bp + 32);
            bf16x8 b2v = *(const bf16x8*)(bp + 64);
            f32x4 acc = (f32x4){0.f, 0.f, 0.f, 0.f};
            acc = __builtin_amdgcn_mfma_f32_16x16x32_bf16(b0, o0, acc, 0, 0, 0);
            acc = __builtin_amdgcn_mfma_f32_16x16x32_bf16(b1, o1, acc, 0, 0, 0);
            acc = __builtin_amdgcn_mfma_f32_16x16x32_bf16(b2v, o2, acc, 0, 0, 0);
            const float4 b4 = *(const float4*)&bo[ct * 16 + lk * 4];
            float4 v;
            v.x = acc[0] + b4.x; v.y = acc[1] + b4.y;
            v.z = acc[2] + b4.z; v.w = acc[3] + b4.w;
            *(float4*)&st[(wv * 16 + lr) * LDST + ct * 16 + lk * 4] = v;
        }
    }
    // No barrier: LN2 reads st rows [wv*16, wv*16+16) = own-wave rows.

    // ---- M1: LN2 from st (LDS), write h2b (own-wave rows). R12 arithmetic
    //      EXACT (contiguous 24-sum + xor1/2; sum order numerics-critical). ----
    {
        const int l = lt, p = lp;
        float s0 = 0.f, s1 = 0.f;
        #pragma unroll
        for (int c0 = 0; c0 < 24; ++c0) {
            float v = st[l * LDST + p * 24 + c0];
            s0 += v; s1 += v * v;
        }
        s0 += __shfl_xor(s0, 1); s1 += __shfl_xor(s1, 1);
        s0 += __shfl_xor(s0, 2); s1 += __shfl_xor(s1, 2);
        float mean = s0 * (1.f / 96.f);
        float var  = fmaxf(s1 * (1.f / 96.f) - mean * mean, 0.f);
        float rstd = rsqrtf(var + 1e-5f);
        #pragma unroll
        for (int c0 = 0; c0 < 24; ++c0) {
            int c = p * 24 + c0;
            float v = st[l * LDST + c];
            h2b[l * LDH + c] = f2bf((v - mean) * rstd * ln2w[c] + ln2b[c]);
        }
    }
    __syncthreads();   // h2b(LN2) + st complete; vt dead beyond here

    // ---- M2: MLP, swapped GEMMs, PING-PONG act buffers (vtact <-> h2b).
    //      a1 frags loaded BEFORE the loop; their lgkm drain happens at the
    //      first ready-barrier (h0,s0) -> first h2b-act write at (h0,s1) is
    //      safe. Buffer rewrite at step i+2 fenced by step-i+1 barrier. ----
    short* actQ0 = vtact;
    short* actQ1 = h2b;
    bf16x8 a1[4][3];
    #pragma unroll
    for (int rt = 0; rt < 4; ++rt)
        #pragma unroll
        for (int ks = 0; ks < 3; ++ks)
            a1[rt][ks] = *(const bf16x8*)&h2b[(rt * 16 + lr) * LDH + ks * 32 + lk * 8];

    f32x4 acc2[2][3];   // swapped: tok = wr*32+rt*16+lr, oc = wc*48+ct*16+lk*4+r
    #pragma unroll
    for (int rt = 0; rt < 2; ++rt)
        #pragma unroll
        for (int ct = 0; ct < 3; ++ct) acc2[rt][ct] = (f32x4){0.f, 0.f, 0.f, 0.f};

    for (int half = 0; half < 2; ++half) {
        const int oc0w = half * 192 + wv * 48;
        f32x4 acc1[4][3];   // swapped: tok = rt*16+lr, oc = oc0w+ct*16+lk*4+r
        #pragma unroll
        for (int rt = 0; rt < 4; ++rt)
            #pragma unroll
            for (int ct = 0; ct < 3; ++ct) acc1[rt][ct] = (f32x4){0.f, 0.f, 0.f, 0.f};

        #pragma unroll
        for (int ct = 0; ct < 3; ++ct) {
            const short* bp = w1b + (oc0w + ct * 16 + lr) * 96 + lk * 8;
            bf16x8 bg0 = *(const bf16x8*)(bp);
            bf16x8 bg1 = *(const bf16x8*)(bp + 32);
            bf16x8 bg2 = *(const bf16x8*)(bp + 64);
            #pragma unroll
            for (int rt = 0; rt < 4; ++rt) {
                acc1[rt][ct] = __builtin_amdgcn_mfma_f32_16x16x32_bf16(bg0, a1[rt][0], acc1[rt][ct], 0, 0, 0);
                acc1[rt][ct] = __builtin_amdgcn_mfma_f32_16x16x32_bf16(bg1, a1[rt][1], acc1[rt][ct], 0, 0, 0);
                acc1[rt][ct] = __builtin_amdgcn_mfma_f32_16x16x32_bf16(bg2, a1[rt][2], acc1[rt][ct], 0, 0, 0);
            }
        }

        for (int sub = 0; sub < 2; ++sub) {
            short* actQ = (sub == 0) ? actQ0 : actQ1;   // ping-pong
            // waves whose 48 cols fall in quarter `sub` write act (bias+GELU)
            if (wr == sub) {
                #pragma unroll
                for (int ct = 0; ct < 3; ++ct) {
                    const float4 b14 = *(const float4*)&b1[oc0w + ct * 16 + lk * 4];
                    const int lcolb = wc * 48 + ct * 16 + lk * 4;  // col within quarter
                    #pragma unroll
                    for (int rt = 0; rt < 4; ++rt) {
                        s16x4 pk;
                        pk[0] = f2bf(gelu_f(acc1[rt][ct][0] + b14.x));
                        pk[1] = f2bf(gelu_f(acc1[rt][ct][1] + b14.y));
                        pk[2] = f2bf(gelu_f(acc1[rt][ct][2] + b14.z));
                        pk[3] = f2bf(gelu_f(acc1[rt][ct][3] + b14.w));
                        *(s16x4*)&actQ[(rt * 16 + lr) * LDAQ + lcolb] = pk;
                    }
                }
            }
            __syncthreads();           // actQ(quarter) ready (drains lgkm/writes)

            // GEMM2 slice: k = half*192 + sub*96 .. +96 (swapped)
            #pragma unroll
            for (int ks = 0; ks < 3; ++ks) {
                bf16x8 a2[2];
                #pragma unroll
                for (int rt = 0; rt < 2; ++rt)
                    a2[rt] = *(const bf16x8*)&actQ[(wr * 32 + rt * 16 + lr) * LDAQ + ks * 32 + lk * 8];
                #pragma unroll
                for (int ct = 0; ct < 3; ++ct) {
                    bf16x8 bw = *(const bf16x8*)(w2b + (wc * 48 + ct * 16 + lr) * 384
                                                  + half * 192 + sub * 96 + ks * 32 + lk * 8);
                    #pragma unroll
                    for (int rt = 0; rt < 2; ++rt)
                        acc2[rt][ct] = __builtin_amdgcn_mfma_f32_16x16x32_bf16(bw, a2[rt], acc2[rt][ct], 0, 0, 0);
                }
            }
            // no trailing barrier: next quarter uses the OTHER buffer; its
            // ready-barrier provides the write-after-read ordering.
        }
    }

    // ---- M3: residual + bias into st, float4 RMW (disjoint 2x2 regions).
    //      All st writes (P6) precede the pre-M2 barrier -> RMW safe. ----
    #pragma unroll
    for (int ct = 0; ct < 3; ++ct) {
        const int colb = wc * 48 + ct * 16 + lk * 4;
        const float4 b24 = *(const float4*)&b2[colb];
        #pragma unroll
        for (int rt = 0; rt < 2; ++rt) {
            const int row = wr * 32 + rt * 16 + lr;
            float4 v = *(const float4*)&st[row * LDST + colb];
            v.x += acc2[rt][ct][0] + b24.x;
            v.y += acc2[rt][ct][1] + b24.y;
            v.z += acc2[rt][ct][2] + b24.z;
            v.w += acc2[rt][ct][3] + b24.w;
            *(float4*)&st[row * LDST + colb] = v;
        }
    }
    __syncthreads();

    // ---- P7: write-back ((lt,lp) float4 map — R15-proven; un-roll cancels
    //      the roll via per-thread tb) ----
    {
        const float* srow = &st[lt * LDST + lp * 24];
        float* orow = out + tb + lp * 24;
        #pragma unroll
        for (int jj = 0; jj < 6; ++jj)
            ((float4*)orow)[jj] = ((const float4*)srow)[jj];
    }
}

// ---------------------------------------------------------------------------
extern "C" void kernel_launch(void* const* d_in, const int* in_sizes, int n_in,
                              void* d_out, int out_size, void* d_ws, size_t ws_size,
                              hipStream_t stream) {
    const float* x    = (const float*)d_in[0];
    const float* ln1w = (const float*)d_in[1];
    const float* ln1b = (const float*)d_in[2];
    const float* wqkv = (const float*)d_in[3];   // [288,96]
    const float* bqkv = (const float*)d_in[4];
    const float* wo   = (const float*)d_in[5];   // [96,96]
    const float* bo   = (const float*)d_in[6];
    const float* ln2w = (const float*)d_in[7];
    const float* ln2b = (const float*)d_in[8];
    const float* w1   = (const float*)d_in[9];   // [384,96]
    const float* b1   = (const float*)d_in[10];
    const float* w2   = (const float*)d_in[11];  // [96,384]
    const float* b2   = (const float*)d_in[12];
    float* out = (float*)d_out;

    short* ws  = (short*)d_ws;
    short* wqb = ws;            // 27648
    short* wob = ws + 27648;    // 9216
    short* w1b = ws + 36864;    // 36864
    short* w2b = ws + 73728;    // 36864   (total 221184 B)

    prep_bf16<<<432, 256, 0, stream>>>(wqkv, wo, w1, w2, ws);
    attn_mlp<<<NW, 256, 0, stream>>>(x, ln1w, ln1b, wqb, bqkv, wob, bo,
                                     ln2w, ln2b, w1b, b1, w2b, b2, out);
}